// Round 4
// baseline (113.923 us; speedup 1.0000x reference)
//
#include <hip/hip_runtime.h>

typedef __attribute__((ext_vector_type(4))) float f32x4;
typedef __attribute__((ext_vector_type(8))) short bf16x8;
typedef __attribute__((ext_vector_type(4))) unsigned int u32x4;

#define IDIM    128
#define HID     64
#define TDEPTH  6
#define MTILE   64
#define NWAVES  6
#define BLOCK   (NWAVES * 64)
#define T_TILES 2            // grid = 65536/(64*2) = 512 blocks = 2 blocks/CU

__device__ __forceinline__ unsigned short f2bf(float f) {
    unsigned int u = __builtin_bit_cast(unsigned int, f);
    unsigned int r = (u + 0x7FFFu + ((u >> 16) & 1u)) >> 16;  // RNE
    return (unsigned short)r;
}

// Pack two fp32 -> one u32 of 2 bf16 (RNE)
__device__ __forceinline__ unsigned int f2bf_pk(float f0, float f1) {
    unsigned int u0 = __builtin_bit_cast(unsigned int, f0);
    unsigned int u1 = __builtin_bit_cast(unsigned int, f1);
    unsigned int t0 = u0 + 0x7FFFu + ((u0 >> 16) & 1u);
    unsigned int t1 = u1 + 0x7FFFu + ((u1 >> 16) & 1u);
    return (t1 & 0xFFFF0000u) | (t0 >> 16);
}

// Wave k owns chain node (2^k - 1). Round-3 lesson: 1 block/CU left every
// barrier/latency exposed (kernel ~34us vs ~6us of actual work). This version
// targets 2 blocks/CU (grid 512, VGPR<=170 via launch_bounds(384,3), LDS 20KB):
// cross-block overlap hides stage/epilogue latency, so the reg-prefetch (24
// VGPR) is dropped and xs is single-buffered. 2 barriers/tile; pp double-
// buffered so tile t's out-write defers past the next barrier with no race.
// d_ws unused (harness poison fill is unconditional — round-3 finding).
__global__ __launch_bounds__(BLOCK, 3)
void sdt_kernel(const float* __restrict__ x, const float* __restrict__ W1,
                const float* __restrict__ b1, const float* __restrict__ W2,
                const float* __restrict__ b2, const float* __restrict__ leaf,
                float* __restrict__ out) {
    __shared__ unsigned short xs[MTILE][IDIM + 8];   // single buffer; +8 pad
    __shared__ float p_lds[TDEPTH][MTILE];
    __shared__ float pp[2][4][MTILE];                // double-buffered fold partials
    __shared__ float leaf_lds[64];

    const int tid   = threadIdx.x;
    const int tile0 = blockIdx.x * T_TILES;

    const int wave = tid >> 6;
    const int lane = tid & 63;
    const int node = (1 << wave) - 1;                // 0,1,3,7,15,31
    const int lcol = lane & 15;
    const int lq   = lane >> 4;

    if (tid < 64) leaf_lds[tid] = leaf[tid];

    const float4* xv = reinterpret_cast<const float4*>(x);

    // ---- stage tile 0: fp32 -> bf16 LDS (coalesced float4) ----
    {
        const float4* xt = xv + (size_t)tile0 * (MTILE * IDIM / 4);
        for (int f = tid; f < MTILE * (IDIM / 4); f += BLOCK) {
            int row = f >> 5, c4 = f & 31;
            float4 v = xt[f];
            unsigned long long pk =
                (unsigned long long)f2bf(v.x) |
                ((unsigned long long)f2bf(v.y) << 16) |
                ((unsigned long long)f2bf(v.z) << 32) |
                ((unsigned long long)f2bf(v.w) << 48);
            *reinterpret_cast<unsigned long long*>(&xs[row][c4 * 4]) = pk;
        }
    }

    // ---- build W1 B-fragments once per block, resident in VGPRs ----
    // B-frag: lane holds B[k = ks*32 + lq*8 + j][n = ct*16 + lcol]
    bf16x8 bfrag[4][4];
    {
        const float* wsrc = W1 + (size_t)node * IDIM * HID + lcol;
        #pragma unroll
        for (int ks = 0; ks < 4; ks++) {
            const int k0 = ks * 32 + lq * 8;
            #pragma unroll
            for (int ct = 0; ct < 4; ct++) {
                const float* wc = wsrc + (size_t)k0 * HID + ct * 16;
                u32x4 pk;
                #pragma unroll
                for (int jp = 0; jp < 4; jp++)
                    pk[jp] = f2bf_pk(wc[(2 * jp) * HID], wc[(2 * jp + 1) * HID]);
                bfrag[ks][ct] = __builtin_bit_cast(bf16x8, pk);
            }
        }
    }

    float b1v[4], w2v[4];
    #pragma unroll
    for (int ct = 0; ct < 4; ct++) {
        int col = ct * 16 + lcol;
        b1v[ct] = b1[node * HID + col];
        w2v[ct] = W2[node * HID + col];
    }
    const float bias2 = b2[node];

    __syncthreads();                                  // xs(0) + leaf_lds ready

    for (int t = 0; t < T_TILES; ++t) {
        // ---- GEMM: 64x64 per wave, K=128, bfrag resident ----
        f32x4 acc[4][4];
        #pragma unroll
        for (int rt = 0; rt < 4; rt++)
            #pragma unroll
            for (int ct = 0; ct < 4; ct++)
                acc[rt][ct] = (f32x4){0.f, 0.f, 0.f, 0.f};
        #pragma unroll
        for (int ks = 0; ks < 4; ks++) {
            #pragma unroll
            for (int rt = 0; rt < 4; rt++) {
                bf16x8 afrag = *reinterpret_cast<const bf16x8*>(
                    &xs[rt * 16 + lcol][ks * 32 + lq * 8]);
                #pragma unroll
                for (int ct = 0; ct < 4; ct++)
                    acc[rt][ct] = __builtin_amdgcn_mfma_f32_16x16x32_bf16(
                        afrag, bfrag[ks][ct], acc[rt][ct], 0, 0, 0);
            }
        }

        // ---- epilogue: relu, dot W2, sigmoid -> p_lds ----
        // C layout: col = ct*16 + lcol, row = rt*16 + lq*4 + r
        #pragma unroll
        for (int rt = 0; rt < 4; rt++) {
            #pragma unroll
            for (int r = 0; r < 4; r++) {
                float s = 0.f;
                #pragma unroll
                for (int ct = 0; ct < 4; ct++) {
                    float v = acc[rt][ct][r] + b1v[ct];
                    v = v > 0.f ? v : 0.f;
                    s += v * w2v[ct];
                }
                #pragma unroll
                for (int d = 1; d < 16; d <<= 1)
                    s += __shfl_xor(s, d, 64);
                float p = 1.f / (1.f + __expf(-(s + bias2)));
                if (lcol == 0)
                    p_lds[wave][rt * 16 + lq * 4 + r] = p;
            }
        }
        __syncthreads();   // bar1: p_lds(t) ready; all xs reads of tile t done

        // ---- deferred out-write of tile t-1 (pp[(t-1)&1] stable) ----
        if (t > 0 && tid < MTILE) {
            const float* q = &pp[(t - 1) & 1][0][0];
            out[(size_t)(tile0 + t - 1) * MTILE + tid] =
                (q[0 * MTILE + tid] + q[1 * MTILE + tid]) +
                (q[2 * MTILE + tid] + q[3 * MTILE + tid]);
        }

        // ---- fold partials (4 waves) -> pp[t&1] ----
        if (tid < 4 * MTILE) {
            int row = tid & (MTILE - 1);
            int ch  = tid >> 6;
            float q0 = p_lds[0][row];
            float q1 = p_lds[1][row];
            float q2 = p_lds[2][row];
            float q3 = p_lds[3][row];
            float p4 = p_lds[4][row];
            float p5 = p_lds[5][row];
            float f4 = (ch & 1) ? p4 : 1.f - p4;
            float f5 = (ch & 2) ? p5 : 1.f - p5;
            const float* lf = leaf_lds + ch * 16;
            float tt[8];
            #pragma unroll
            for (int j = 0; j < 8; j++) {
                float a = lf[2 * j], b = lf[2 * j + 1];
                tt[j] = a + q0 * (b - a);
            }
            #pragma unroll
            for (int j = 0; j < 4; j++) tt[j] = tt[2 * j] + q1 * (tt[2 * j + 1] - tt[2 * j]);
            #pragma unroll
            for (int j = 0; j < 2; j++) tt[j] = tt[2 * j] + q2 * (tt[2 * j + 1] - tt[2 * j]);
            float s = tt[0] + q3 * (tt[1] - tt[0]);
            pp[t & 1][ch][row] = f4 * f5 * s;
        }

        // ---- stage tile t+1 (overwrites xs; reads done at bar1) ----
        if (t + 1 < T_TILES) {
            const float4* xt = xv + (size_t)(tile0 + t + 1) * (MTILE * IDIM / 4);
            for (int f = tid; f < MTILE * (IDIM / 4); f += BLOCK) {
                int row = f >> 5, c4 = f & 31;
                float4 v = xt[f];
                unsigned long long pk =
                    (unsigned long long)f2bf(v.x) |
                    ((unsigned long long)f2bf(v.y) << 16) |
                    ((unsigned long long)f2bf(v.z) << 32) |
                    ((unsigned long long)f2bf(v.w) << 48);
                *reinterpret_cast<unsigned long long*>(&xs[row][c4 * 4]) = pk;
            }
        }
        __syncthreads();   // bar2: xs(t+1) ready; pp(t) ready
    }

    // ---- final tile's out-write ----
    if (tid < MTILE) {
        const float* q = &pp[(T_TILES - 1) & 1][0][0];
        out[(size_t)(tile0 + T_TILES - 1) * MTILE + tid] =
            (q[0 * MTILE + tid] + q[1 * MTILE + tid]) +
            (q[2 * MTILE + tid] + q[3 * MTILE + tid]);
    }
}

extern "C" void kernel_launch(void* const* d_in, const int* in_sizes, int n_in,
                              void* d_out, int out_size, void* d_ws, size_t ws_size,
                              hipStream_t stream) {
    const float* x    = (const float*)d_in[0];
    const float* W1   = (const float*)d_in[1];
    const float* b1   = (const float*)d_in[2];
    const float* W2   = (const float*)d_in[3];
    const float* b2   = (const float*)d_in[4];
    const float* leaf = (const float*)d_in[5];
    float* out = (float*)d_out;

    const int Bn = in_sizes[0] / IDIM;               // 65536
    const int nblocks = Bn / (MTILE * T_TILES);      // 512 = 2 blocks/CU

    (void)d_ws; (void)ws_size;                       // unused (poison fill is unconditional anyway)
    sdt_kernel<<<nblocks, BLOCK, 0, stream>>>(x, W1, b1, W2, b2, leaf, out);
}